// Round 11
// baseline (334.816 us; speedup 1.0000x reference)
//
#include <hip/hip_runtime.h>

typedef _Float16 f16;
typedef _Float16 f16x8 __attribute__((ext_vector_type(8)));
typedef _Float16 f16x4 __attribute__((ext_vector_type(4)));
typedef _Float16 f16x2 __attribute__((ext_vector_type(2)));
typedef float f32x4 __attribute__((ext_vector_type(4)));
typedef unsigned long long u64;

#define MFMA16(a, b, c) __builtin_amdgcn_mfma_f32_16x16x32_f16((a), (b), (c), 0, 0, 0)

constexpr float QSCALE = 0.18033688011112042f;  // (1/sqrt(64)) * log2(e)

// direct global->LDS 16B/lane: lds dest = wave-uniform base + lane*16
__device__ __forceinline__ void gll16(const f16* g, f16* l) {
  __builtin_amdgcn_global_load_lds((__attribute__((address_space(1))) void*)(g),
                                   (__attribute__((address_space(3))) void*)(l),
                                   16, 0, 0);
}

struct CDesc { const float* src; f16* dst; unsigned n4, off4; };
struct TDesc { const float* src; f16* dst; int K, blk_off; };

// ---------------- fused prep: masks->bits (x4 vectorized) + fp32->f16 convert +
// ---------------- weight transpose. One launch, block-range dispatch. ----------------
struct PrepArgs {
  const void* m1; const void* m2; const void* m3; u64* mb;
  CDesc cd[4];
  TDesc td[8];
};

__global__ __launch_bounds__(256) void prep_kernel(PrepArgs a) {
  int bid = blockIdx.x;
  int tid = threadIdx.x;
  __shared__ float tile[32][33];
  if (bid < 16384) {  // ---- masks: wave handles 256 elems; lane i: {i,64+i,128+i,192+i}
    int l = tid & 63;
    unsigned probe = ((const unsigned*)a.m1)[tid & 15];
    u64 vote = __ballot(probe <= 1u);
    bool int_mode = ((vote & 0xFFFFull) == 0xFFFFull);
    unsigned gw = bid * 4u + (tid >> 6);
    unsigned e0 = gw * 256u;
    unsigned row = e0 >> 12, j0 = e0 & 4095;
    const void* src; size_t base;
    if (j0 < 1024) { src = a.m1; base = (size_t)row * 1024 + j0; }
    else if (j0 < 2048) { src = a.m2; base = (size_t)row * 1024 + (j0 - 1024); }
    else { src = a.m3; base = (size_t)row * 2048 + (j0 - 2048); }
    u64 b0, b1, b2, b3;
    if (int_mode) {
      const int* s = (const int*)src + base + l;
      b0 = __ballot(s[0] != 0);   b1 = __ballot(s[64] != 0);
      b2 = __ballot(s[128] != 0); b3 = __ballot(s[192] != 0);
    } else {
      const unsigned char* s = (const unsigned char*)src + base + l;
      b0 = __ballot(s[0] != 0);   b1 = __ballot(s[64] != 0);
      b2 = __ballot(s[128] != 0); b3 = __ballot(s[192] != 0);
    }
    u64 b = b0;
    if (l == 1) b = b1; else if (l == 2) b = b2; else if (l == 3) b = b3;
    if (l < 4) a.mb[gw * 4 + l] = b;
    return;
  }
  if (bid < 25600) {  // ---- convert
    unsigned t = (bid - 16384) * 256u + tid;
    CDesc s;
    if (t >= a.cd[3].off4) s = a.cd[3];
    else if (t >= a.cd[2].off4) s = a.cd[2];
    else if (t >= a.cd[1].off4) s = a.cd[1];
    else s = a.cd[0];
    unsigned i = t - s.off4;
    if (i >= s.n4) return;
    float4 v = ((const float4*)s.src)[i];
    f16x4 o;
    o[0] = (f16)v.x; o[1] = (f16)v.y; o[2] = (f16)v.z; o[3] = (f16)v.w;
    ((f16x4*)s.dst)[i] = o;
    return;
  }
  // ---- weight transpose
  int tb = bid - 25600;
  int di = 0;
#pragma unroll
  for (int i = 1; i < 8; i++)
    if (tb >= a.td[i].blk_off) di = i;
  TDesc d = a.td[di];
  int lb = tb - d.blk_off;
  int ktiles = d.K >> 5;
  int kt = lb % ktiles, nt = lb / ktiles;
  int k0 = kt * 32, n0 = nt * 32;
  int tc = tid & 31, tr = tid >> 5;
#pragma unroll
  for (int i = 0; i < 4; i++) {
    int kl = tr + 8 * i;
    tile[tc][kl] = d.src[(size_t)(k0 + kl) * 512 + n0 + tc];
  }
  __syncthreads();
#pragma unroll
  for (int i = 0; i < 4; i++) {
    int nl = tr + 8 * i;
    d.dst[(size_t)(n0 + nl) * d.K + k0 + tc] = (f16)tile[nl][tc];
  }
}

// ---------------- tiled projection GEMM: 128x128 tile, global_load_lds staging ----------------
// Unpadded 128x32 LDS tiles (row = 64B): fragment-read banks tile evenly -> b128
// floor, no pad needed. mode 3 (out-projection) fuses the split-KV combine into
// A-staging: reads 4 PO partials + 4 LW sums, normalizes, writes combined f16
// tile to LDS via registers (identical numerics to the old combine kernel).
struct PDesc {
  const f16* A; const f16* B; const float* bias; void* out;
  int K, mode, logNloc, nk_off, blk_off, ntiles;
};
struct PArgs { PDesc d[8]; };

__global__ __launch_bounds__(256) void proj_kernel(PArgs args, int bid_base,
                                                   const f16* __restrict__ PO,
                                                   const float* __restrict__ LW) {
  int bid = blockIdx.x + bid_base;
  int di = 0;
#pragma unroll
  for (int i = 1; i < 8; i++)
    if (bid >= args.d[i].blk_off) di = i;
  PDesc d = args.d[di];
  int lb = bid - d.blk_off;
  int bn = lb % d.ntiles, bm = lb / d.ntiles;
  int tid = threadIdx.x;
  int lane = tid & 63, wv = tid >> 6;
  int wm = wv >> 1, wn = wv & 1;
  int r16 = lane & 15, q4 = lane >> 4;
  int K = d.K;
  int m0 = bm * 128, n0 = bn * 128;

  __shared__ f16 As[2][128 * 32];
  __shared__ f16 Bs[2][128 * 32];

  int srow = 32 * wv + (lane >> 2);
  int scol = 8 * (lane & 3);
  const f16* agw = d.A + (size_t)(m0 + srow) * K + scol;
  const f16* bgw = d.B + (size_t)(n0 + srow) * K + scol;
  bool fuse = (d.mode == 3);
  auto stage = [&](int p, int kk) {
#pragma unroll
    for (int cc = 0; cc < 2; cc++) {
      if (!fuse) {
        gll16(agw + (size_t)(16 * cc) * K + kk, As[p] + 1024 * wv + 512 * cc);
      } else {
        // fused combine: A-tile element (r, col) = sum_ks PO[ks][r][col] / l(r,col)
        int r = m0 + srow + 16 * cc;
        int col = kk + scol;
        int bb = r >> 10, q = r & 1023;
        int h = col >> 6;
        size_t lidx = (size_t)(bb * 8 + h) * 1024 + q;
        float l = LW[lidx] + LW[32768 + lidx] + LW[65536 + lidx] + LW[98304 + lidx];
        float inv = 1.0f / l;
        size_t poff = (size_t)r * 512 + col;
        f16x8 o0 = *(const f16x8*)(PO + poff);
        f16x8 o1 = *(const f16x8*)(PO + 2097152 + poff);
        f16x8 o2 = *(const f16x8*)(PO + 4194304 + poff);
        f16x8 o3 = *(const f16x8*)(PO + 6291456 + poff);
        f16x8 cmb;
#pragma unroll
        for (int j = 0; j < 8; j++)
          cmb[j] = (f16)(((float)o0[j] + (float)o1[j] + (float)o2[j] + (float)o3[j]) * inv);
        *(f16x8*)(As[p] + 1024 * wv + 512 * cc + (lane >> 2) * 32 + scol) = cmb;
      }
      gll16(bgw + (size_t)(16 * cc) * K + kk, Bs[p] + 1024 * wv + 512 * cc);
    }
  };

  f32x4 c[4][4] = {};
  int nk = K >> 5;
  stage(0, 0);
  __syncthreads();
  for (int kt = 0; kt < nk; kt++) {
    int p = kt & 1;
    if (kt + 1 < nk) stage(p ^ 1, (kt + 1) << 5);
    const f16* ab = As[p] + (wm * 64 + r16) * 32 + q4 * 8;
    const f16* bb = Bs[p] + (wn * 64 + r16) * 32 + q4 * 8;
    f16x8 af[4], bf[4];
#pragma unroll
    for (int t = 0; t < 4; t++) af[t] = *(const f16x8*)(ab + t * 16 * 32);
#pragma unroll
    for (int u = 0; u < 4; u++) bf[u] = *(const f16x8*)(bb + u * 16 * 32);
#pragma unroll
    for (int t = 0; t < 4; t++)
#pragma unroll
      for (int u = 0; u < 4; u++) c[t][u] = MFMA16(af[t], bf[u], c[t][u]);
    __syncthreads();
  }

  int msk = (1 << d.logNloc) - 1;
#pragma unroll
  for (int t = 0; t < 4; t++) {
#pragma unroll
    for (int u = 0; u < 4; u++) {
#pragma unroll
      for (int r = 0; r < 4; r++) {
        int gm = m0 + wm * 64 + t * 16 + q4 * 4 + r;
        int cn = n0 + wn * 64 + u * 16 + r16;
        float val = c[t][u][r] + (d.mode == 2 ? d.bias[gm] : d.bias[cn]);
        if (d.mode == 0) {
          int hh = cn >> 6, dd = cn & 63, bb = gm >> 10, nn = gm & 1023;
          ((f16*)d.out)[(((size_t)bb * 8 + hh) * 1024 + nn) * 64 + dd] = (f16)(val * QSCALE);
        } else if (d.mode == 1) {
          int hh = cn >> 6, dd = cn & 63, bb = gm >> d.logNloc, nn = d.nk_off + (gm & msk);
          ((f16*)d.out)[(((size_t)bb * 8 + hh) * 4096 + nn) * 64 + dd] = (f16)val;
        } else if (d.mode == 2) {
          int hh = gm >> 6, dd = gm & 63, bb = cn >> d.logNloc, nn = d.nk_off + (cn & msk);
          ((f16*)d.out)[(((size_t)bb * 8 + hh) * 64 + dd) * 4096 + nn] = (f16)val;
        } else {
          ((float*)d.out)[(size_t)gm * 512 + cn] = val;
        }
      }
    }
  }
}

// ---------------- flash attention: 32 q-rows/wave, split-KV x4, LDS-shared KV ----------------
// R9 staging structure (measured best): register prefetch distance 2 via
// loadKV/writeKV, stride-72-padded LDS tiles (2-way alias = free). The R10
// direct-DMA variant halved bank conflicts but LOST 7us -- the binding factor
// is staging latency tolerance (distance 2 vs 1), not LDS conflicts.
// S^T = K*Q^T QK (swapped MFMA operands) -> lane holds 4 consecutive k for one
// q -> P written with 2x v_cvt_pkrtz + one ds_write_b64 (conflict-free).
// Fixed-base softmax (exp2 domain, no max): partials additive across splits;
// each split writes unnormalized o (f16) + l (f32); outproj fuses the combine.
// LDS 47KB -> 3 blocks/CU. XCD pinning: low 5 bits of blockIdx = (b,h).
__global__ __launch_bounds__(256, 3) void attn_kernel(const f16* __restrict__ Qh,
                                                      const f16* __restrict__ Kh,
                                                      const f16* __restrict__ Vt,
                                                      const u64* __restrict__ MB,
                                                      f16* __restrict__ PO,
                                                      float* __restrict__ LW) {
  int lin = blockIdx.x;
  int hb = lin & 31;
  int rest = lin >> 5;          // 0..31 = qt(8) x ks(4)
  int qt = rest & 7, ks = rest >> 3;
  int h = hb & 7, b = hb >> 3;
  int tid = threadIdx.x;
  int lane = tid & 63, wv = tid >> 6;
  int r16 = lane & 15, q4 = lane >> 4;
  int q0 = qt * 128;
  int bh = b * 8 + h;

  const f16* qp = Qh + ((size_t)bh * 1024 + q0 + wv * 32) * 64;
  f16x8 aq[2][2];
#pragma unroll
  for (int s = 0; s < 2; s++) {
    aq[s][0] = *(const f16x8*)(qp + (s * 16 + r16) * 64 + q4 * 8);
    aq[s][1] = *(const f16x8*)(qp + (s * 16 + r16) * 64 + q4 * 8 + 32);
  }
  const f16* kg = Kh + (size_t)bh * (4096 * 64) + (size_t)ks * 1024 * 64;
  const f16* vg = Vt + (size_t)bh * (64 * 4096) + ks * 1024;
  // mask: lane (r16) owns q-row (q0 + wv*32 + s*16 + r16); one u64 per tile per s
  const u64* mrow = MB + ((size_t)b * 1024 + q0 + wv * 32 + r16) * 64 + ks * 16;

  __shared__ f16 kls[2][64 * 72];
  __shared__ f16 vls[2][64 * 72];
  __shared__ f16 pbuf[4][32 * 40];
  f16* pw = pbuf[wv];

  int c_row = tid >> 3;        // 0..31
  int c_col = (tid & 7) * 8;   // halfword offset
  f16x8 kr0, kr1, vr0, vr1;
  auto loadKV = [&](int j0) {
    const f16* kp = kg + (size_t)(j0 + c_row) * 64 + c_col;
    kr0 = *(const f16x8*)kp;
    kr1 = *(const f16x8*)(kp + 32 * 64);
    const f16* vp = vg + (size_t)c_row * 4096 + j0 + c_col;
    vr0 = *(const f16x8*)vp;
    vr1 = *(const f16x8*)(vp + 32 * 4096);
  };
  auto writeKV = [&](int p) {
    *(f16x8*)(kls[p] + c_row * 72 + c_col) = kr0;
    *(f16x8*)(kls[p] + (c_row + 32) * 72 + c_col) = kr1;
    *(f16x8*)(vls[p] + c_row * 72 + c_col) = vr0;
    *(f16x8*)(vls[p] + (c_row + 32) * 72 + c_col) = vr1;
  };

  f16x8 ones;
#pragma unroll
  for (int i = 0; i < 8; i++) ones[i] = (f16)1.0f;
  f32x4 accl[2] = {};
  f32x4 acc[2][4] = {};

  loadKV(0);
  writeKV(0);
  loadKV(64);
  __syncthreads();

  for (int jt = 0; jt < 16; jt++) {
    int p = jt & 1;
    if (jt < 15) writeKV(p ^ 1);
    if (jt < 14) loadKV((jt + 2) * 64);
    u64 wrd[2];
#pragma unroll
    for (int s = 0; s < 2; s++) wrd[s] = mrow[s * 16 * 64 + jt];
    const f16* kb_ = kls[p];
    const f16* vb_ = vls[p];
#pragma unroll
    for (int ph = 0; ph < 2; ph++) {
      // S^T for this k-half -> P half-tile (rows q, cols k 0..31 of pw)
#pragma unroll
      for (int th = 0; th < 2; th++) {
        int t = ph * 2 + th;
        f16x8 k0 = *(const f16x8*)(kb_ + (t * 16 + r16) * 72 + q4 * 8);
        f16x8 k1 = *(const f16x8*)(kb_ + (t * 16 + r16) * 72 + q4 * 8 + 32);
#pragma unroll
        for (int s = 0; s < 2; s++) {
          f32x4 z{};
          z = MFMA16(k0, aq[s][0], z);   // A=K-frag, B=Q-frag -> D = S^T
          z = MFMA16(k1, aq[s][1], z);
          u64 w = wrd[s] >> (t * 16 + q4 * 4);
          float p0 = (w & 1) ? __builtin_amdgcn_exp2f(z[0]) : 0.0f;
          float p1 = (w & 2) ? __builtin_amdgcn_exp2f(z[1]) : 0.0f;
          float p2 = (w & 4) ? __builtin_amdgcn_exp2f(z[2]) : 0.0f;
          float p3 = (w & 8) ? __builtin_amdgcn_exp2f(z[3]) : 0.0f;
          f16x2 lo = __builtin_bit_cast(f16x2, __builtin_amdgcn_cvt_pkrtz(p0, p1));
          f16x2 hi = __builtin_bit_cast(f16x2, __builtin_amdgcn_cvt_pkrtz(p2, p3));
          f16x4 pk = __builtin_shufflevector(lo, hi, 0, 1, 2, 3);
          *(f16x4*)(pw + (s * 16 + r16) * 40 + th * 16 + q4 * 4) = pk;
        }
      }
      // wave-local LDS visibility (DS ops are per-wave in-order)
      asm volatile("s_waitcnt lgkmcnt(0)" ::: "memory");
      f16x8 ap[2];
#pragma unroll
      for (int s = 0; s < 2; s++)
        ap[s] = *(const f16x8*)(pw + (s * 16 + r16) * 40 + q4 * 8);
#pragma unroll
      for (int dt = 0; dt < 4; dt++) {
        f16x8 vf = *(const f16x8*)(vb_ + (dt * 16 + r16) * 72 + ph * 32 + q4 * 8);
#pragma unroll
        for (int s = 0; s < 2; s++) acc[s][dt] = MFMA16(ap[s], vf, acc[s][dt]);
      }
#pragma unroll
      for (int s = 0; s < 2; s++) accl[s] = MFMA16(ap[s], ones, accl[s]);
    }
    __syncthreads();
  }

  // epilogue: unnormalized partials (additive across ks under fixed-base softmax)
  f16* pok = PO + (size_t)ks * (4096 * 512);
#pragma unroll
  for (int s = 0; s < 2; s++)
#pragma unroll
    for (int r = 0; r < 4; r++) {
      int rowg = b * 1024 + q0 + wv * 32 + s * 16 + q4 * 4 + r;
      f16* orow = pok + (size_t)rowg * 512 + h * 64 + r16;
#pragma unroll
      for (int dt = 0; dt < 4; dt++) orow[dt * 16] = (f16)(acc[s][dt][r]);
    }
  if (r16 == 0) {
    float* lk = LW + (size_t)ks * 32768 + (size_t)bh * 1024 + q0 + wv * 32;
#pragma unroll
    for (int s = 0; s < 2; s++)
#pragma unroll
      for (int r = 0; r < 4; r++) lk[s * 16 + q4 * 4 + r] = accl[s][r];
  }
}

extern "C" void kernel_launch(void* const* d_in, const int* in_sizes, int n_in,
                              void* d_out, int out_size, void* d_ws, size_t ws_size,
                              hipStream_t stream) {
  (void)in_sizes; (void)n_in; (void)out_size; (void)ws_size;
  const float* x  = (const float*)d_in[0];
  const float* c1 = (const float*)d_in[1];
  const float* c2 = (const float*)d_in[2];
  const float* c3 = (const float*)d_in[3];
  const void* m1 = d_in[4];
  const void* m2 = d_in[5];
  const void* m3 = d_in[6];
  const float* Wq = (const float*)d_in[7];   const float* bq = (const float*)d_in[8];
  const float* Wk1 = (const float*)d_in[9];  const float* bk1 = (const float*)d_in[10];
  const float* Wv1 = (const float*)d_in[11]; const float* bv1 = (const float*)d_in[12];
  const float* Wk2 = (const float*)d_in[13]; const float* bk2 = (const float*)d_in[14];
  const float* Wv2 = (const float*)d_in[15]; const float* bv2 = (const float*)d_in[16];
  const float* Wk3 = (const float*)d_in[17]; const float* bk3 = (const float*)d_in[18];
  const float* Wv3 = (const float*)d_in[19]; const float* bv3 = (const float*)d_in[20];
  const float* Wo = (const float*)d_in[21];  const float* bo = (const float*)d_in[22];

  char* ws = (char*)d_ws;
  size_t off = 0;
  auto alloc = [&](size_t bytes) {
    void* p = ws + off;
    off = (off + bytes + 255) & ~(size_t)255;
    return p;
  };
  f16* xb   = (f16*)alloc(2097152 * 2);  // 4096x512
  f16* c1b  = (f16*)alloc(2097152 * 2);  // 4096x512
  f16* c2b  = (f16*)alloc(3145728 * 2);  // 4096x768
  f16* c3b  = (f16*)alloc(2097152 * 2);  // 8192x256
  f16* wqt  = (f16*)alloc(262144 * 2);
  f16* wk1t = (f16*)alloc(262144 * 2);
  f16* wk2t = (f16*)alloc(393216 * 2);
  f16* wk3t = (f16*)alloc(131072 * 2);
  f16* wv1t = (f16*)alloc(262144 * 2);
  f16* wv2t = (f16*)alloc(393216 * 2);
  f16* wv3t = (f16*)alloc(131072 * 2);
  f16* wot  = (f16*)alloc(262144 * 2);
  f16* qh   = (f16*)alloc(2097152 * 2);  // [4][8][1024][64]
  f16* kh   = (f16*)alloc(8388608 * 2);  // [4][8][4096][64]
  f16* vt   = (f16*)alloc(8388608 * 2);  // [4][8][64][4096]
  f16* ao   = (f16*)alloc(2097152 * 2);  // (unused; kept for offset stability)
  u64* mbits = (u64*)alloc(2097152);     // [4][1024][64] words

  // attention partials ALIAS the xb..c3b region (dead after proj main):
  // PO: 4 x 4096x512 f16 = 16.78 MB at ws+0; LW: 4 x 32768 f32 after it.
  f16* po = (f16*)ws;
  float* lw = (float*)(ws + 16777216);

  // 1) fused prep: mask bits + fp32->f16 convert + weight transpose
  PrepArgs pra;
  pra.m1 = m1; pra.m2 = m2; pra.m3 = m3; pra.mb = mbits;
  pra.cd[0] = {x,  xb,  524288, 0};
  pra.cd[1] = {c1, c1b, 524288, 524288};
  pra.cd[2] = {c2, c2b, 786432, 1048576};
  pra.cd[3] = {c3, c3b, 524288, 1835008};
  pra.td[0] = {Wq,  wqt,  512, 0};
  pra.td[1] = {Wk1, wk1t, 512, 256};
  pra.td[2] = {Wk2, wk2t, 768, 512};
  pra.td[3] = {Wk3, wk3t, 256, 896};
  pra.td[4] = {Wv1, wv1t, 512, 1024};
  pra.td[5] = {Wv2, wv2t, 768, 1280};
  pra.td[6] = {Wv3, wv3t, 256, 1664};
  pra.td[7] = {Wo,  wot,  512, 1792};
  prep_kernel<<<27648, 256, 0, stream>>>(pra);

  // 2) fused projections, 128x128 tiles (Q, K1..3 normal; V1..3 as V^T)
  PArgs pa;
  //            A     B     bias  out    K   mode logN nk    blk   ntiles
  pa.d[0] = {xb,   wqt,  bq,  qh,    512, 0, 10, 0,    0,    4};   // 32x4 = 128
  pa.d[1] = {c1b,  wk1t, bk1, kh,    512, 1, 10, 0,    128,  4};   // 128
  pa.d[2] = {c2b,  wk2t, bk2, kh,    768, 1, 10, 1024, 256,  4};   // 128
  pa.d[3] = {c3b,  wk3t, bk3, kh,    256, 1, 11, 2048, 384,  4};   // 64x4 = 256
  pa.d[4] = {wv1t, c1b,  bv1, vt,    512, 2, 10, 0,    640,  32};  // 4x32 = 128
  pa.d[5] = {wv2t, c2b,  bv2, vt,    768, 2, 10, 1024, 768,  32};  // 128
  pa.d[6] = {wv3t, c3b,  bv3, vt,    256, 2, 11, 2048, 896,  64};  // 4x64 = 256
  pa.d[7] = {po,   wot,  bo,  d_out, 512, 3, 10, 0,    1152, 4};   // 32x4 = 128
  proj_kernel<<<1152, 256, 0, stream>>>(pa, 0, po, lw);

  // 3) flash attention (R9 staging, S^T QK, split-KV x4, XCD-pinned) -> partials
  attn_kernel<<<1024, 256, 0, stream>>>(qh, kh, vt, mbits, po, lw);

  // 4) output projection with fused combine -> fp32 d_out (descriptor 7)
  proj_kernel<<<128, 256, 0, stream>>>(pa, 1152, po, lw);
}